// Round 8
// baseline (90.769 us; speedup 1.0000x reference)
//
#include <hip/hip_runtime.h>
#include <hip/hip_bf16.h>

#define B_ 32
#define N_ 256
#define C_ 512
#define O_ 512
#define S_ 512

#define KT  64     // weight k-tile (floats)
#define WST 72     // wt row stride in shorts: 144 B -> 2-way bank alias on b128 reads = free

typedef __attribute__((ext_vector_type(8))) short short8;
typedef __attribute__((ext_vector_type(4))) float f32x4;

// packed f32x2 -> bf16x2 (RNE) — lowers to v_cvt_pk_bf16_f32
__device__ __forceinline__ unsigned pk2(float a, float b) {
    union { __hip_bfloat162 h; unsigned u; } v;
    v.h = __float22bfloat162_rn(make_float2(a, b));
    return v.u;
}

// Barrier that does NOT drain vmcnt: LDS ordering via lgkmcnt(0) only.
// Global loads issued before it stay in flight across it (T4 counted-vmcnt idea;
// the compiler still emits counted vmcnt before the registers' first use).
__device__ __forceinline__ void barrier_nodrain() {
    asm volatile("s_waitcnt lgkmcnt(0)" ::: "memory");
    __builtin_amdgcn_s_barrier();
    __builtin_amdgcn_sched_barrier(0);
}

// R4 geometry (KT=64 dbuf LDS, 2 blocks/CU) + non-draining barriers +
// packed cvt + fp32 ssq folded into the commit phase.
__global__ __launch_bounds__(256, 2) void tml_kernel(const float* __restrict__ x,
                                                     const float* __restrict__ s,
                                                     const float* __restrict__ weight,
                                                     const float* __restrict__ bias,
                                                     const float* __restrict__ s_w,
                                                     const float* __restrict__ s_b,
                                                     float* __restrict__ out) {
    // XCD-aware bijective remap (nwg=1024 divisible by 8)
    const int h       = blockIdx.x;
    const int logical = (h & 7) * 128 + (h >> 3);
    const int n       = logical >> 2;
    const int ot      = logical & 3;

    const int tid  = threadIdx.x;
    const int wv   = tid >> 6;
    const int lane = tid & 63;
    const int l16  = lane & 15;
    const int lk   = lane >> 4;
    const int srow = tid >> 4;   // staging row-in-group (0..15)
    const int scol = tid & 15;   // staging 16B slot

    __shared__ short xs[B_][C_ + 8];     // bf16 x (33.3 KB)
    __shared__ short wt[2][128][WST];    // bf16 weight k-tiles, dbuf (36.9 KB)
    __shared__ float ssq_lds[128];       // fp32 sumsq per panel o-row
    __shared__ float sm_lds[B_];

    const float* wbase = weight + (size_t)n * (O_ * C_) + (size_t)(ot * 128) * C_ + scol * 4;

    float4 rgA[8], rgB[8];
    // prologue: tile 0 in flight before the smap/x phases
#pragma unroll
    for (int i = 0; i < 8; ++i)
        rgA[i] = *(const float4*)(wbase + (size_t)(i * 16 + srow) * C_);

    // ---- fused smap: sm_lds[b] = gain * dot(s[b,:], s_w[n,:]) + s_b[n]
    {
        const int b    = tid >> 3;
        const int slot = tid & 7;
        const float* sp = s   + (size_t)b * S_ + slot * 64;
        const float* wp = s_w + (size_t)n * S_ + slot * 64;
        float sum = 0.f;
#pragma unroll
        for (int j = 0; j < 16; ++j) {
            float4 sv  = *(const float4*)(sp + 4 * j);
            float4 wv4 = *(const float4*)(wp + 4 * j);
            sum += sv.x * wv4.x + sv.y * wv4.y + sv.z * wv4.z + sv.w * wv4.w;
        }
        sum += __shfl_xor(sum, 1, 64);
        sum += __shfl_xor(sum, 2, 64);
        sum += __shfl_xor(sum, 4, 64);
        if (slot == 0) sm_lds[b] = sum * 0.04419417382415922f + s_b[n];
    }

    // ---- stage x[:, n, :] -> bf16 LDS (packed cvt)
    const float* xn = x + (size_t)n * C_;
#pragma unroll
    for (int r = 0; r < 16; ++r) {
        int i  = r * 256 + tid;
        int b  = i >> 7;
        int c4 = (i & 127) << 2;
        const float4 v = *(const float4*)(xn + (size_t)b * (N_ * C_) + c4);
        *(uint2*)&xs[b][c4] = make_uint2(pk2(v.x, v.y), pk2(v.z, v.w));
    }

    float ssqr[8];
#pragma unroll
    for (int i = 0; i < 8; ++i) ssqr[i] = 0.f;

    f32x4 acc00 = {0.f,0.f,0.f,0.f}, acc01 = acc00, acc10 = acc00, acc11 = acc00;

    barrier_nodrain();   // xs + sm_lds ready

    // STEP T: issue tile T+1 loads; commit tile T (fp32 ssq + packed cvt -> LDS);
    // non-draining barrier; MFMA tile T. Compiler auto-emits vmcnt(8) before the
    // first RC use, so tile T+1's loads stay in flight across barrier + MFMA.
#define STEP(T, RC, RN, PB)                                                       \
    {                                                                             \
        if ((T) + 1 < 8) {                                                        \
            _Pragma("unroll")                                                     \
            for (int i = 0; i < 8; ++i)                                           \
                RN[i] = *(const float4*)(wbase + (size_t)(i * 16 + srow) * C_     \
                                         + ((T) + 1) * KT);                       \
        }                                                                         \
        _Pragma("unroll")                                                         \
        for (int i = 0; i < 8; ++i) {                                             \
            ssqr[i] += RC[i].x * RC[i].x + RC[i].y * RC[i].y                      \
                     + RC[i].z * RC[i].z + RC[i].w * RC[i].w;                     \
            *(uint2*)&wt[PB][i * 16 + srow][scol * 4] =                           \
                make_uint2(pk2(RC[i].x, RC[i].y), pk2(RC[i].z, RC[i].w));         \
        }                                                                         \
        if ((T) == 7) {                                                           \
            _Pragma("unroll")                                                     \
            for (int i = 0; i < 8; ++i) {                                         \
                float v = ssqr[i];                                                \
                v += __shfl_xor(v, 1, 64);                                        \
                v += __shfl_xor(v, 2, 64);                                        \
                v += __shfl_xor(v, 4, 64);                                        \
                v += __shfl_xor(v, 8, 64);                                        \
                if (scol == 0) ssq_lds[i * 16 + srow] = v;                        \
            }                                                                     \
        }                                                                         \
        barrier_nodrain();                                                        \
        _Pragma("unroll")                                                         \
        for (int ks = 0; ks < 2; ++ks) {                                          \
            const int co = ks * 32 + lk * 8;                                      \
            short8 a0 = *(const short8*)&xs[l16][(T) * KT + co];                  \
            short8 a1 = *(const short8*)&xs[16 + l16][(T) * KT + co];             \
            short8 b0 = *(const short8*)&wt[PB][wv * 32 + l16][co];               \
            short8 b1 = *(const short8*)&wt[PB][wv * 32 + 16 + l16][co];          \
            acc00 = __builtin_amdgcn_mfma_f32_16x16x32_bf16(a0, b0, acc00, 0,0,0);\
            acc10 = __builtin_amdgcn_mfma_f32_16x16x32_bf16(a1, b0, acc10, 0,0,0);\
            acc01 = __builtin_amdgcn_mfma_f32_16x16x32_bf16(a0, b1, acc01, 0,0,0);\
            acc11 = __builtin_amdgcn_mfma_f32_16x16x32_bf16(a1, b1, acc11, 0,0,0);\
        }                                                                         \
    }

    STEP(0, rgA, rgB, 0)
    STEP(1, rgB, rgA, 1)
    STEP(2, rgA, rgB, 0)
    STEP(3, rgB, rgA, 1)
    STEP(4, rgA, rgB, 0)
    STEP(5, rgB, rgA, 1)
    STEP(6, rgA, rgB, 0)
    STEP(7, rgB, rgA, 1)
#undef STEP

    // ---- epilogue. C/D layout: col = lane&15, row = (lane>>4)*4 + reg
#pragma unroll
    for (int f = 0; f < 2; ++f) {
        const int orow = wv * 32 + f * 16 + l16;       // panel-local o row
        const int o    = ot * 128 + orow;
        const float bv = bias[n * O_ + o];
        const float sq = ssq_lds[orow];
        const f32x4 am0 = f ? acc01 : acc00;
        const f32x4 am1 = f ? acc11 : acc10;
#pragma unroll
        for (int r = 0; r < 4; ++r) {
            {
                const int brow = lk * 4 + r;
                const float smv = sm_lds[brow];
                const float dec = rsqrtf(smv * smv * sq + 1e-8f);
                out[(size_t)brow * (N_ * O_) + n * O_ + o] = am0[r] * smv * dec + bv;
            }
            {
                const int brow = 16 + lk * 4 + r;
                const float smv = sm_lds[brow];
                const float dec = rsqrtf(smv * smv * sq + 1e-8f);
                out[(size_t)brow * (N_ * O_) + n * O_ + o] = am1[r] * smv * dec + bv;
            }
        }
    }
}

extern "C" void kernel_launch(void* const* d_in, const int* in_sizes, int n_in,
                              void* d_out, int out_size, void* d_ws, size_t ws_size,
                              hipStream_t stream) {
    const float* x      = (const float*)d_in[0];
    const float* s      = (const float*)d_in[1];
    const float* weight = (const float*)d_in[2];
    const float* bias   = (const float*)d_in[3];
    const float* s_w    = (const float*)d_in[4];
    const float* s_b    = (const float*)d_in[5];
    float* out = (float*)d_out;

    tml_kernel<<<N_ * 4, 256, 0, stream>>>(x, s, weight, bias, s_w, s_b, out);
}

// Round 9
// 63.030 us; speedup vs baseline: 1.4401x; 1.4401x over previous
//
#include <hip/hip_runtime.h>

#define B_ 32
#define N_ 256
#define C_ 512
#define O_ 512
#define S_ 512

#define KT  64                // weight k-tile (floats)
#define NKT (C_ / KT)         // 8 tiles
#define WST 72                // wt row stride in shorts: 144 B, 16B-aligned

typedef __attribute__((ext_vector_type(8))) short short8;
typedef __attribute__((ext_vector_type(4))) float f32x4;

__device__ __forceinline__ short f2bf(float f) {
    union { float f; unsigned u; } v; v.f = f;
    unsigned r = v.u + 0x7fffu + ((v.u >> 16) & 1u);  // RNE (inputs finite)
    return (short)(r >> 16);
}
__device__ __forceinline__ float bf2f(short s) {
    union { unsigned u; float f; } v; v.u = ((unsigned)(unsigned short)s) << 16;
    return v.f;
}

// Non-draining barrier: LDS ordering only (lgkmcnt(0)); vmcnt untouched, so
// global weight loads stay in flight across the barrier. __syncthreads would
// lower to s_waitcnt vmcnt(0) lgkmcnt(0) + s_barrier (full load-queue drain).
__device__ __forceinline__ void nd_barrier() {
    asm volatile("s_waitcnt lgkmcnt(0)" ::: "memory");
    __builtin_amdgcn_s_barrier();
}

// R4 structure verbatim (63.2 us baseline); ONLY change: barriers don't drain vmcnt.
__global__ __launch_bounds__(256, 2) void tml_kernel(const float* __restrict__ x,
                                                     const float* __restrict__ s,
                                                     const float* __restrict__ weight,
                                                     const float* __restrict__ bias,
                                                     const float* __restrict__ s_w,
                                                     const float* __restrict__ s_b,
                                                     float* __restrict__ out) {
    // XCD-aware bijective remap (nwg=1024 divisible by 8)
    const int h       = blockIdx.x;
    const int logical = (h & 7) * 128 + (h >> 3);
    const int n       = logical >> 2;
    const int ot      = logical & 3;

    const int tid  = threadIdx.x;
    const int wv   = tid >> 6;
    const int lane = tid & 63;
    const int l16  = lane & 15;
    const int lk   = lane >> 4;

    __shared__ short xs[B_][C_ + 8];        // bf16 x, stride 520 (conflict-safe)
    __shared__ short wt[2][128][WST];       // bf16 weight k-tiles, double-buffered
    __shared__ float sm_lds[B_];

    // ---- weight staging map: 16 consecutive threads cover one row's 256 B k-slice
    const int srow = tid >> 4;   // 0..15 (row within 16-row group)
    const int scol = tid & 15;   // 16 B slot (4 floats)
    const float* wbase = weight + (size_t)n * (O_ * C_) + (size_t)(ot * 128) * C_ + scol * 4;

    float4 rg0[8], rg1[8];
    // issue tile 0 loads now; latency hides under smap + x staging
#pragma unroll
    for (int i = 0; i < 8; ++i)
        rg0[i] = *(const float4*)(wbase + (size_t)(i * 16 + srow) * C_);

    // ---- fused smap: sm_lds[b] = gain * dot(s[b,:], s_w[n,:]) + s_b[n]
    {
        const int b    = tid >> 3;
        const int slot = tid & 7;
        const float* sp = s   + (size_t)b * S_ + slot * 64;
        const float* wp = s_w + (size_t)n * S_ + slot * 64;
        float sum = 0.f;
#pragma unroll
        for (int j = 0; j < 16; ++j) {
            float4 sv  = *(const float4*)(sp + 4 * j);
            float4 wv4 = *(const float4*)(wp + 4 * j);
            sum += sv.x * wv4.x + sv.y * wv4.y + sv.z * wv4.z + sv.w * wv4.w;
        }
        sum += __shfl_xor(sum, 1, 64);
        sum += __shfl_xor(sum, 2, 64);
        sum += __shfl_xor(sum, 4, 64);
        if (slot == 0) sm_lds[b] = sum * 0.04419417382415922f + s_b[n];
    }

    // ---- stage x[:, n, :] -> bf16 LDS
    const float* xn = x + (size_t)n * C_;
#pragma unroll
    for (int r = 0; r < 16; ++r) {
        int i  = r * 256 + tid;
        int b  = i >> 7;
        int c4 = (i & 127) << 2;
        const float4 v = *(const float4*)(xn + (size_t)b * (N_ * C_) + c4);
        short4 hh;
        hh.x = f2bf(v.x); hh.y = f2bf(v.y); hh.z = f2bf(v.z); hh.w = f2bf(v.w);
        *(short4*)&xs[b][c4] = hh;
    }

    f32x4 acc00 = {0.f,0.f,0.f,0.f}, acc01 = acc00, acc10 = acc00, acc11 = acc00;
    float ssq0 = 0.f, ssq1 = 0.f;

    // One K-step: prefetch next tile, commit current regs->LDS, nd-barrier, MFMA.
    // Single barrier per tile is safe under double-buffering (buffer PB is
    // rewritten only two tiles later, with a barrier in between; each wave's
    // ds_reads of PB complete before it passes the next barrier via lgkmcnt(0)).
#define STEP(T, RCUR, RNXT, PB)                                                   \
    {                                                                             \
        if ((T) + 1 < NKT) {                                                      \
            _Pragma("unroll")                                                     \
            for (int i = 0; i < 8; ++i)                                           \
                RNXT[i] = *(const float4*)(wbase + (size_t)(i * 16 + srow) * C_   \
                                           + ((T) + 1) * KT);                     \
        }                                                                         \
        _Pragma("unroll")                                                         \
        for (int i = 0; i < 8; ++i) {                                             \
            short4 hv;                                                            \
            hv.x = f2bf(RCUR[i].x); hv.y = f2bf(RCUR[i].y);                       \
            hv.z = f2bf(RCUR[i].z); hv.w = f2bf(RCUR[i].w);                       \
            *(short4*)&wt[PB][i * 16 + srow][scol * 4] = hv;                      \
        }                                                                         \
        nd_barrier();                                                             \
        _Pragma("unroll")                                                         \
        for (int ks = 0; ks < KT / 32; ++ks) {                                    \
            const int co = ks * 32 + lk * 8;                                      \
            short8 a0 = *(const short8*)&xs[l16][(T) * KT + co];                  \
            short8 a1 = *(const short8*)&xs[16 + l16][(T) * KT + co];             \
            short8 b0 = *(const short8*)&wt[PB][wv * 32 + l16][co];               \
            short8 b1 = *(const short8*)&wt[PB][wv * 32 + 16 + l16][co];          \
            _Pragma("unroll")                                                     \
            for (int j = 0; j < 8; ++j) {                                         \
                float f0 = bf2f(b0[j]), f1 = bf2f(b1[j]);                         \
                ssq0 += f0 * f0; ssq1 += f1 * f1;                                 \
            }                                                                     \
            acc00 = __builtin_amdgcn_mfma_f32_16x16x32_bf16(a0, b0, acc00, 0,0,0);\
            acc10 = __builtin_amdgcn_mfma_f32_16x16x32_bf16(a1, b0, acc10, 0,0,0);\
            acc01 = __builtin_amdgcn_mfma_f32_16x16x32_bf16(a0, b1, acc01, 0,0,0);\
            acc11 = __builtin_amdgcn_mfma_f32_16x16x32_bf16(a1, b1, acc11, 0,0,0);\
        }                                                                         \
    }

    STEP(0, rg0, rg1, 0)
    STEP(1, rg1, rg0, 1)
    STEP(2, rg0, rg1, 0)
    STEP(3, rg1, rg0, 1)
    STEP(4, rg0, rg1, 0)
    STEP(5, rg1, rg0, 1)
    STEP(6, rg0, rg1, 0)
    STEP(7, rg1, rg0, 1)
#undef STEP

    // ssq partial per k-group; reduce over lk (xor 16, 32)
    ssq0 += __shfl_xor(ssq0, 16, 64);  ssq0 += __shfl_xor(ssq0, 32, 64);
    ssq1 += __shfl_xor(ssq1, 16, 64);  ssq1 += __shfl_xor(ssq1, 32, 64);

    // ---- epilogue. C/D layout: col = lane&15, row = (lane>>4)*4 + reg
    const int ob = ot * 128 + wv * 32;
#pragma unroll
    for (int f = 0; f < 2; ++f) {
        const int o  = ob + f * 16 + l16;
        const float bv = bias[n * O_ + o];
        const float sq = f ? ssq1 : ssq0;
        const f32x4 am0 = f ? acc01 : acc00;
        const f32x4 am1 = f ? acc11 : acc10;
#pragma unroll
        for (int r = 0; r < 4; ++r) {
            {
                const int brow = lk * 4 + r;
                const float smv = sm_lds[brow];
                const float dec = rsqrtf(smv * smv * sq + 1e-8f);
                out[(size_t)brow * (N_ * O_) + n * O_ + o] = am0[r] * smv * dec + bv;
            }
            {
                const int brow = 16 + lk * 4 + r;
                const float smv = sm_lds[brow];
                const float dec = rsqrtf(smv * smv * sq + 1e-8f);
                out[(size_t)brow * (N_ * O_) + n * O_ + o] = am1[r] * smv * dec + bv;
            }
        }
    }
}

extern "C" void kernel_launch(void* const* d_in, const int* in_sizes, int n_in,
                              void* d_out, int out_size, void* d_ws, size_t ws_size,
                              hipStream_t stream) {
    const float* x      = (const float*)d_in[0];
    const float* s      = (const float*)d_in[1];
    const float* weight = (const float*)d_in[2];
    const float* bias   = (const float*)d_in[3];
    const float* s_w    = (const float*)d_in[4];
    const float* s_b    = (const float*)d_in[5];
    float* out = (float*)d_out;

    tml_kernel<<<N_ * 4, 256, 0, stream>>>(x, s, weight, bias, s_w, s_b, out);
}

// Round 10
// 53.717 us; speedup vs baseline: 1.6898x; 1.1734x over previous
//
#include <hip/hip_runtime.h>

#define B_ 32
#define N_ 256
#define C_ 512
#define O_ 512
#define S_ 512

#define KT  32                // weight k-tile (floats)
#define NKT (C_ / KT)         // 16 tiles
#define WST 40                // wt row stride in shorts: 80 B -> phase-20 bank spread

typedef __attribute__((ext_vector_type(8))) short short8;
typedef __attribute__((ext_vector_type(4))) float f32x4;

__device__ __forceinline__ short f2bf(float f) {
    union { float f; unsigned u; } v; v.f = f;
    unsigned r = v.u + 0x7fffu + ((v.u >> 16) & 1u);  // RNE (inputs finite)
    return (short)(r >> 16);
}
__device__ __forceinline__ float bf2f(short s) {
    union { unsigned u; float f; } v; v.u = ((unsigned)(unsigned short)s) << 16;
    return v.f;
}

// Non-draining barrier: LDS ordering only; weight loads stay in flight across it.
__device__ __forceinline__ void nd_barrier() {
    asm volatile("s_waitcnt lgkmcnt(0)" ::: "memory");
    __builtin_amdgcn_s_barrier();
}

// One block per n: 256 blocks x 512 thr (8 waves) = exactly 1 block/CU,
// single generation, x staged once per n, smap computed once per n.
// Wave w owns o-rows [w*64, w*64+64); 16 k-tiles of KT=32, dbuf LDS.
__global__ __launch_bounds__(512, 2) void tml_kernel(const float* __restrict__ x,
                                                     const float* __restrict__ s,
                                                     const float* __restrict__ weight,
                                                     const float* __restrict__ bias,
                                                     const float* __restrict__ s_w,
                                                     const float* __restrict__ s_b,
                                                     float* __restrict__ out) {
    const int n    = blockIdx.x;
    const int tid  = threadIdx.x;
    const int wv   = tid >> 6;    // 0..7
    const int lane = tid & 63;
    const int l16  = lane & 15;
    const int lk   = lane >> 4;

    __shared__ short xs[B_][C_ + 8];     // bf16 x (33.3 KB)
    __shared__ short wt[2][O_][WST];     // bf16 weight k-tiles, dbuf (80 KB)
    __shared__ float sm_lds[B_];

    // staging map: 8 threads cover one row's 128 B k-slice; thread does rows srow+64i
    const int srow = tid >> 3;   // 0..63
    const int scol = tid & 7;    // 16 B slot
    const float* wbase = weight + (size_t)n * (O_ * C_) + scol * 4;

    float4 rg0[8], rg1[8];
    // tile 0 in flight before smap + x staging
#pragma unroll
    for (int i = 0; i < 8; ++i)
        rg0[i] = *(const float4*)(wbase + (size_t)(i * 64 + srow) * C_);

    // ---- smap (once per n): sm_lds[b] = gain * dot(s[b,:], s_w[n,:]) + s_b[n]
    {
        const int b    = tid >> 4;       // 0..31
        const int slot = tid & 15;       // 16 threads per b
        const float* sp = s   + (size_t)b * S_ + slot * 32;
        const float* wp = s_w + (size_t)n * S_ + slot * 32;
        float sum = 0.f;
#pragma unroll
        for (int j = 0; j < 8; ++j) {
            float4 sv  = *(const float4*)(sp + 4 * j);
            float4 wv4 = *(const float4*)(wp + 4 * j);
            sum += sv.x * wv4.x + sv.y * wv4.y + sv.z * wv4.z + sv.w * wv4.w;
        }
        sum += __shfl_xor(sum, 1, 64);
        sum += __shfl_xor(sum, 2, 64);
        sum += __shfl_xor(sum, 4, 64);
        sum += __shfl_xor(sum, 8, 64);
        if (slot == 0) sm_lds[b] = sum * 0.04419417382415922f + s_b[n];
    }

    // ---- stage x[:, n, :] -> bf16 LDS (once per n)
    const float* xn = x + (size_t)n * C_;
#pragma unroll
    for (int r = 0; r < 8; ++r) {
        int i  = r * 512 + tid;
        int b  = i >> 7;
        int c4 = (i & 127) << 2;
        const float4 v = *(const float4*)(xn + (size_t)b * (N_ * C_) + c4);
        short4 hh;
        hh.x = f2bf(v.x); hh.y = f2bf(v.y); hh.z = f2bf(v.z); hh.w = f2bf(v.w);
        *(short4*)&xs[b][c4] = hh;
    }

    f32x4 acc[4][2];
#pragma unroll
    for (int f = 0; f < 4; ++f)
#pragma unroll
        for (int m = 0; m < 2; ++m) acc[f][m] = (f32x4){0.f, 0.f, 0.f, 0.f};
    float ssq[4] = {0.f, 0.f, 0.f, 0.f};

    // STEP T: issue tile T+1 loads; commit tile T regs->LDS; nd-barrier; MFMA tile T.
    // Buffer PB rewritten only at T+2 (after barrier T+1); ds_reads of tile T
    // complete before this wave passes barrier T+1 (lgkmcnt(0)).
#define STEP(T, RCUR, RNXT, PB)                                                     \
    {                                                                               \
        if ((T) + 1 < NKT) {                                                        \
            _Pragma("unroll")                                                       \
            for (int i = 0; i < 8; ++i)                                             \
                RNXT[i] = *(const float4*)(wbase + (size_t)(i * 64 + srow) * C_     \
                                           + ((T) + 1) * KT);                       \
        }                                                                           \
        _Pragma("unroll")                                                           \
        for (int i = 0; i < 8; ++i) {                                               \
            short4 hv;                                                              \
            hv.x = f2bf(RCUR[i].x); hv.y = f2bf(RCUR[i].y);                         \
            hv.z = f2bf(RCUR[i].z); hv.w = f2bf(RCUR[i].w);                         \
            *(short4*)&wt[PB][i * 64 + srow][scol * 4] = hv;                        \
        }                                                                           \
        nd_barrier();                                                               \
        {                                                                           \
            const int co = lk * 8;                                                  \
            short8 a0 = *(const short8*)&xs[l16][(T) * KT + co];                    \
            short8 a1 = *(const short8*)&xs[16 + l16][(T) * KT + co];               \
            _Pragma("unroll")                                                       \
            for (int f = 0; f < 4; ++f) {                                           \
                short8 bf = *(const short8*)&wt[PB][wv * 64 + f * 16 + l16][co];    \
                _Pragma("unroll")                                                   \
                for (int j = 0; j < 8; ++j) {                                       \
                    float fv = bf2f(bf[j]); ssq[f] += fv * fv;                      \
                }                                                                   \
                acc[f][0] = __builtin_amdgcn_mfma_f32_16x16x32_bf16(a0, bf,         \
                                                          acc[f][0], 0, 0, 0);     \
                acc[f][1] = __builtin_amdgcn_mfma_f32_16x16x32_bf16(a1, bf,         \
                                                          acc[f][1], 0, 0, 0);     \
            }                                                                       \
        }                                                                           \
    }

    STEP(0,  rg0, rg1, 0)
    STEP(1,  rg1, rg0, 1)
    STEP(2,  rg0, rg1, 0)
    STEP(3,  rg1, rg0, 1)
    STEP(4,  rg0, rg1, 0)
    STEP(5,  rg1, rg0, 1)
    STEP(6,  rg0, rg1, 0)
    STEP(7,  rg1, rg0, 1)
    STEP(8,  rg0, rg1, 0)
    STEP(9,  rg1, rg0, 1)
    STEP(10, rg0, rg1, 0)
    STEP(11, rg1, rg0, 1)
    STEP(12, rg0, rg1, 0)
    STEP(13, rg1, rg0, 1)
    STEP(14, rg0, rg1, 0)
    STEP(15, rg1, rg0, 1)
#undef STEP

    // ssq partial per lk k-slice; reduce over lk (same o = l16 column)
#pragma unroll
    for (int f = 0; f < 4; ++f) {
        ssq[f] += __shfl_xor(ssq[f], 16, 64);
        ssq[f] += __shfl_xor(ssq[f], 32, 64);
    }

    // ---- epilogue. C/D layout: col = lane&15, row = (lane>>4)*4 + reg
#pragma unroll
    for (int f = 0; f < 4; ++f) {
        const int o    = wv * 64 + f * 16 + l16;
        const float bv = bias[n * O_ + o];
        const float sq = ssq[f];
#pragma unroll
        for (int m = 0; m < 2; ++m) {
#pragma unroll
            for (int r = 0; r < 4; ++r) {
                const int brow  = m * 16 + lk * 4 + r;
                const float smv = sm_lds[brow];
                const float dec = rsqrtf(smv * smv * sq + 1e-8f);
                out[(size_t)brow * (N_ * O_) + n * O_ + o] =
                    acc[f][m][r] * smv * dec + bv;
            }
        }
    }
}

extern "C" void kernel_launch(void* const* d_in, const int* in_sizes, int n_in,
                              void* d_out, int out_size, void* d_ws, size_t ws_size,
                              hipStream_t stream) {
    const float* x      = (const float*)d_in[0];
    const float* s      = (const float*)d_in[1];
    const float* weight = (const float*)d_in[2];
    const float* bias   = (const float*)d_in[3];
    const float* s_w    = (const float*)d_in[4];
    const float* s_b    = (const float*)d_in[5];
    float* out = (float*)d_out;

    tml_kernel<<<N_, 512, 0, stream>>>(x, s, weight, bias, s_w, s_b, out);
}